// Round 2
// baseline (198.064 us; speedup 1.0000x reference)
//
#include <hip/hip_runtime.h>

// Problem constants (B,N,D,U) = (8,2048,512,128)
#define BB 8
#define NN 2048
#define DD 512
#define UU 128
#define SPLITS 4
#define KSPLIT 512   // keys per split
#define NT (KSPLIT / 64)

typedef __bf16 bf16_t;
typedef __bf16 bf16x4 __attribute__((ext_vector_type(4)));
typedef __bf16 bf16x8 __attribute__((ext_vector_type(8)));
typedef float floatx4 __attribute__((ext_vector_type(4)));

__device__ __forceinline__ floatx4 mfma16(bf16x8 a, bf16x8 b, floatx4 c) {
  return __builtin_amdgcn_mfma_f32_16x16x32_bf16(a, b, c, 0, 0, 0);
}

// XOR swizzle on 16B granules: granule g of row r lives at column ((g^(r&7))*8).
#define SW(r, g) ((((g) ^ ((r) & 7)) * 8))

// async 16B global->LDS copy (dest must be wave-uniform base + lane*16)
__device__ __forceinline__ void gld_lds16(const bf16_t* g, bf16_t* l) {
  __builtin_amdgcn_global_load_lds(
      (const __attribute__((address_space(1))) unsigned int*)g,
      (__attribute__((address_space(3))) unsigned int*)l, 16, 0, 0);
}

// ---------------------------------------------------------------------------
// Kernel 1: cast X (fp32) -> bf16, stored granule-swizzled
// ---------------------------------------------------------------------------
__global__ __launch_bounds__(256) void cast_x_kernel(const float* __restrict__ x,
                                                     bf16_t* __restrict__ xb) {
  int G = blockIdx.x * 256 + threadIdx.x;   // global granule id (8 elems)
  int token = G >> 6;                        // 64 granules per 512-col row
  int g = G & 63;
  int dstg = (g & 56) | ((g & 7) ^ (token & 7));  // swizzle within 64-col chunk
  const float4* src = reinterpret_cast<const float4*>(x) + (size_t)G * 2;
  float4 a = src[0], b = src[1];
  bf16x8 o;
  o[0] = (bf16_t)a.x; o[1] = (bf16_t)a.y; o[2] = (bf16_t)a.z; o[3] = (bf16_t)a.w;
  o[4] = (bf16_t)b.x; o[5] = (bf16_t)b.y; o[6] = (bf16_t)b.z; o[7] = (bf16_t)b.w;
  *reinterpret_cast<bf16x8*>(&xb[(size_t)token * 512 + dstg * 8]) = o;
}

// ---------------------------------------------------------------------------
// Kernel 2: pack weights transposed bf16, granule-swizzled.
// ---------------------------------------------------------------------------
__global__ __launch_bounds__(256) void pack_w_kernel(const float* __restrict__ wq,
                                                     const float* __restrict__ wk,
                                                     const float* __restrict__ wv,
                                                     const float* __restrict__ wo,
                                                     bf16_t* __restrict__ wqkvt,
                                                     bf16_t* __restrict__ wot) {
  int gid = blockIdx.x * 256 + threadIdx.x;
  if (gid < 384 * 512) {
    int nrow = gid >> 9;
    int kdst = gid & 511;
    int ksrc = (kdst & ~56) | (((((kdst >> 3) & 7)) ^ (nrow & 7)) << 3);
    const float* src = (nrow < 128) ? wq : ((nrow < 256) ? wk : wv);
    int n = nrow & 127;
    wqkvt[gid] = (bf16_t)src[ksrc * 128 + n];
  } else {
    int g = gid - 384 * 512;
    int nrow = g >> 7;   // d index (row)
    int kdst = g & 127;  // u index (col)
    int ksrc = (kdst & ~56) | (((((kdst >> 3) & 7)) ^ (nrow & 7)) << 3);
    wot[g] = (bf16_t)wo[ksrc * 512 + nrow];
  }
}

// ---------------------------------------------------------------------------
// Kernel 3: QKV GEMM (128x64 tiles, async swizzled staging).
// ---------------------------------------------------------------------------
__global__ __launch_bounds__(256, 4) void qkv_gemm_kernel(const bf16_t* __restrict__ xb,
                                                          const bf16_t* __restrict__ wqkvt,
                                                          bf16_t* __restrict__ Q,
                                                          bf16_t* __restrict__ K,
                                                          bf16_t* __restrict__ Vt) {
  __shared__ bf16_t lA[128 * 64];
  __shared__ bf16_t lB[64 * 64];
  const int m0 = blockIdx.x * 128;
  const int n0 = blockIdx.y * 64;
  const int tid = threadIdx.x;
  const int w = tid >> 6, lane = tid & 63;
  const int quad = lane >> 4, l15 = lane & 15;

  floatx4 zero4 = {0.f, 0.f, 0.f, 0.f};
  floatx4 acc[2][4];
#pragma unroll
  for (int mi = 0; mi < 2; mi++)
#pragma unroll
    for (int nt = 0; nt < 4; nt++) acc[mi][nt] = zero4;

  for (int kc = 0; kc < 512; kc += 64) {
    __syncthreads();
#pragma unroll
    for (int i = 0; i < 4; i++) {
      int t = tid + i * 256;       // A granule 0..1023
      int r = t >> 3, g = t & 7;
      gld_lds16(&xb[(size_t)(m0 + r) * 512 + kc + g * 8], &lA[t * 8]);
    }
#pragma unroll
    for (int i = 0; i < 2; i++) {
      int t = tid + i * 256;       // B granule 0..511
      int r = t >> 3, g = t & 7;
      gld_lds16(&wqkvt[(size_t)(n0 + r) * 512 + kc + g * 8], &lB[t * 8]);
    }
    asm volatile("s_waitcnt vmcnt(0)" ::: "memory");
    __syncthreads();
#pragma unroll
    for (int kb = 0; kb < 2; kb++) {
      bf16x8 bfr[4];
#pragma unroll
      for (int nt = 0; nt < 4; nt++)
        bfr[nt] = *reinterpret_cast<const bf16x8*>(
            &lB[(nt * 16 + l15) * 64 + SW(l15, kb * 4 + quad)]);
#pragma unroll
      for (int mi = 0; mi < 2; mi++) {
        bf16x8 a = *reinterpret_cast<const bf16x8*>(
            &lA[(w * 32 + mi * 16 + l15) * 64 + SW(l15, kb * 4 + quad)]);
#pragma unroll
        for (int nt = 0; nt < 4; nt++)
          acc[mi][nt] = mfma16(a, bfr[nt], acc[mi][nt]);
      }
    }
  }

#pragma unroll
  for (int mi = 0; mi < 2; mi++)
#pragma unroll
    for (int nt = 0; nt < 4; nt++) {
      int n = n0 + nt * 16 + l15;
#pragma unroll
      for (int r = 0; r < 4; r++) {
        int token = m0 + w * 32 + mi * 16 + quad * 4 + r;
        bf16_t h = (bf16_t)acc[mi][nt][r];
        if (n < 128) {
          Q[(size_t)token * 128 + n] = h;
        } else if (n < 256) {
          int nk = n - 128;
          int nsw = (nk & ~56) | ((((nk >> 3) & 7) ^ (token & 7)) << 3);
          K[(size_t)token * 128 + nsw] = h;
        } else {
          int bidx = token >> 11;
          int t = token & 2047;
          int u = n - 256;
          int tsw = (t & ~56) | ((((t >> 3) & 7) ^ (u & 7)) << 3);
          Vt[((size_t)bidx * 128 + u) * 2048 + tsw] = h;
        }
      }
    }
}

// ---------------------------------------------------------------------------
// Kernel 4: split-K flash attention, PRODUCER/CONSUMER wave specialization.
// Block: 512 threads = 8 waves, 256 queries. Waves 0-3 produce P (read K
// only), waves 4-7 consume (read V + P only) -> per-tile LDS traffic drops
// 40% vs all-waves-read-everything. K/V/P all double-buffered; producers
// work on tile t+1 while consumers work on tile t; one barrier per tile.
// LDS: 2*16K (K) + 2*16K (V) + 2*32K (P) = 128K -> 1 block/CU, 2 waves/SIMD
// (1 producer + 1 consumer per SIMD -> setprio arbitration pays).
// ---------------------------------------------------------------------------
__global__ __launch_bounds__(512, 2) void attn_kernel(const bf16_t* __restrict__ Q,
                                                      const bf16_t* __restrict__ K,
                                                      const bf16_t* __restrict__ Vt,
                                                      bf16_t* __restrict__ Op,
                                                      float* __restrict__ ml) {
  __shared__ bf16_t lK[2][64 * 128];
  __shared__ bf16_t lV[2][128 * 64];
  __shared__ bf16_t lP[2][256 * 64];

  const int b = blockIdx.y;
  const int qb = blockIdx.x;          // q0 = qb*256
  const int s = blockIdx.z;
  const int tid = threadIdx.x;
  const int w = tid >> 6, lane = tid & 63;
  const int quad = lane >> 4, l15 = lane & 15;
  const int rw = w & 3;               // role-local wave index 0..3
  const bool producer = (w < 4);
  const float c = 0.08838834764831845f * 1.4426950408889634f;  // 1/sqrt(U)*log2e

  const int kt0 = s * KSPLIT;
  const bf16_t* kbase = &K[((size_t)b * NN + kt0) * 128];
  const bf16_t* vbase = &Vt[(size_t)b * 128 * 2048 + kt0];

  // Q fragments (producers only): 64 queries/wave, B-operand of S^T
  bf16x8 qf[4][4];
  if (producer) {
#pragma unroll
    for (int mt = 0; mt < 4; mt++) {
      const bf16_t* qrow =
          &Q[((size_t)b * NN + qb * 256 + rw * 64 + mt * 16 + l15) * 128 + quad * 8];
#pragma unroll
      for (int kb = 0; kb < 4; kb++)
        qf[mt][kb] = *reinterpret_cast<const bf16x8*>(qrow + kb * 32);
    }
  }

  float l_part[4] = {0.f, 0.f, 0.f, 0.f};
  floatx4 zero4 = {0.f, 0.f, 0.f, 0.f};
  floatx4 accO[4][8];   // consumers only: 64 q x 128 u
#pragma unroll
  for (int mt = 0; mt < 4; mt++)
#pragma unroll
    for (int ut = 0; ut < 8; ut++) accO[mt][ut] = zero4;

  // staging helpers: 512 threads cover one 16KB tile in 2 gld_lds each
  auto stageK = [&](int t) {
    const bf16_t* src = kbase + (size_t)t * 64 * 128;
    bf16_t* dst = lK[t & 1];
#pragma unroll
    for (int i = 0; i < 2; i++) {
      int g = tid + i * 512;
      gld_lds16(src + (size_t)g * 8, dst + g * 8);
    }
  };
  auto stageV = [&](int t) {
    bf16_t* dst = lV[t & 1];
#pragma unroll
    for (int i = 0; i < 2; i++) {
      int g = tid + i * 512;
      int r = g >> 3, gg = g & 7;
      gld_lds16(vbase + (size_t)r * 2048 + t * 64 + gg * 8, dst + g * 8);
    }
  };

  // producer compute: P[tt] = exp2(c * K[tt]·Q^T), written to lP[tt&1]
  auto computeP = [&](int tt) {
    const bf16_t* kl = lK[tt & 1];
    bf16_t* pb = &lP[tt & 1][rw * 64 * 64];
#pragma unroll
    for (int km = 0; km < 4; km++) {
      floatx4 accS[4];
#pragma unroll
      for (int mt = 0; mt < 4; mt++) accS[mt] = zero4;
      __builtin_amdgcn_s_setprio(1);
#pragma unroll
      for (int kb = 0; kb < 4; kb++) {
        bf16x8 kf = *reinterpret_cast<const bf16x8*>(
            &kl[(km * 16 + l15) * 128 + SW(l15, kb * 4 + quad)]);
#pragma unroll
        for (int mt = 0; mt < 4; mt++)
          accS[mt] = mfma16(kf, qf[mt][kb], accS[mt]);
      }
      __builtin_amdgcn_s_setprio(0);
#pragma unroll
      for (int mt = 0; mt < 4; mt++) {
        float p0 = __builtin_amdgcn_exp2f(accS[mt][0] * c);
        float p1 = __builtin_amdgcn_exp2f(accS[mt][1] * c);
        float p2 = __builtin_amdgcn_exp2f(accS[mt][2] * c);
        float p3 = __builtin_amdgcn_exp2f(accS[mt][3] * c);
        l_part[mt] += (p0 + p1) + (p2 + p3);
        bf16x4 pk;
        pk[0] = (bf16_t)p0; pk[1] = (bf16_t)p1; pk[2] = (bf16_t)p2; pk[3] = (bf16_t)p3;
        int row = mt * 16 + l15;
        int g = km * 2 + (quad >> 1);
        *reinterpret_cast<bf16x4*>(
            &pb[row * 64 + ((g ^ (row & 7)) * 8) + (quad & 1) * 4]) = pk;
      }
    }
  };

  // prologue: land K[0],V[0],K[1]; producers build P[0]
  stageK(0);
  stageV(0);
  stageK(1);
  asm volatile("s_waitcnt vmcnt(0)" ::: "memory");
  __syncthreads();
  if (producer) computeP(0);
  __syncthreads();

  for (int t = 0; t < NT; ++t) {
    // async stage with 1-2 tile lookahead (lands by end-of-iter barrier)
    if (t + 2 < NT) stageK(t + 2);
    if (t + 1 < NT) stageV(t + 1);

    if (producer) {
      if (t + 1 < NT) computeP(t + 1);
    } else {
      // O += P[t] * V[t]
      const bf16_t* pbc = &lP[t & 1][rw * 64 * 64];
      const bf16_t* vl = lV[t & 1];
      __builtin_amdgcn_s_setprio(1);
#pragma unroll
      for (int kb = 0; kb < 2; kb++) {
        bf16x8 pa[4];
#pragma unroll
        for (int mt = 0; mt < 4; mt++)
          pa[mt] = *reinterpret_cast<const bf16x8*>(
              &pbc[(mt * 16 + l15) * 64 + SW(l15, kb * 4 + quad)]);
#pragma unroll
        for (int ut = 0; ut < 8; ut++) {
          bf16x8 bv = *reinterpret_cast<const bf16x8*>(
              &vl[(ut * 16 + l15) * 64 + SW(l15, kb * 4 + quad)]);
#pragma unroll
          for (int mt = 0; mt < 4; mt++)
            accO[mt][ut] = mfma16(pa[mt], bv, accO[mt][ut]);
        }
      }
      __builtin_amdgcn_s_setprio(0);
    }

    asm volatile("s_waitcnt vmcnt(0)" ::: "memory");
    __syncthreads();
  }

  size_t base = ((size_t)(b * 8 + qb) * SPLITS + s);
  if (producer) {
#pragma unroll
    for (int mt = 0; mt < 4; mt++) {
      float v = l_part[mt];
      v += __shfl_xor(v, 16);
      v += __shfl_xor(v, 32);
      l_part[mt] = v;
    }
    if (quad == 0) {
      float* mlp = ml + base * 256 + rw * 64;
#pragma unroll
      for (int mt = 0; mt < 4; mt++) mlp[mt * 16 + l15] = l_part[mt];
    }
  } else {
    bf16_t* op = Op + base * (256 * 128) + (size_t)rw * 64 * 128;
#pragma unroll
    for (int mt = 0; mt < 4; mt++)
#pragma unroll
      for (int ut = 0; ut < 8; ut++)
#pragma unroll
        for (int r = 0; r < 4; r++)
          op[(mt * 16 + quad * 4 + r) * 128 + ut * 16 + l15] =
              (bf16_t)accO[mt][ut][r];
  }
}

// ---------------------------------------------------------------------------
// Kernel 4b: merge split-K partials -> ctx bf16, granule-swizzled.
// Fully coalesced: one 16B granule per thread, lanes sweep granules.
// Grid (64 blk, 16 q-groups); block = 16 q x 128 u.
// ---------------------------------------------------------------------------
__global__ __launch_bounds__(256) void merge_kernel(const bf16_t* __restrict__ Op,
                                                    const float* __restrict__ ml,
                                                    bf16_t* __restrict__ ctx) {
  const int blk = blockIdx.x;                      // b*8 + qb
  const int qloc = blockIdx.y * 16 + (threadIdx.x >> 4);  // 0..255
  const int g = threadIdx.x & 15;                  // granule 0..15

  float L = 0.f;
  float o[8];
#pragma unroll
  for (int j = 0; j < 8; j++) o[j] = 0.f;
#pragma unroll
  for (int s = 0; s < SPLITS; s++) {
    size_t e = (size_t)blk * SPLITS + s;
    L += ml[e * 256 + qloc];
    bf16x8 ch = *reinterpret_cast<const bf16x8*>(&Op[(e * 256 + qloc) * 128 + g * 8]);
#pragma unroll
    for (int j = 0; j < 8; j++) o[j] += (float)ch[j];
  }
  float inv = 1.0f / L;
  int gsw = (g & 8) | ((g & 7) ^ (qloc & 7));
  bf16x8 ch;
#pragma unroll
  for (int j = 0; j < 8; j++) ch[j] = (bf16_t)(o[j] * inv);
  const int bb = blk >> 3, qbl = blk & 7;
  *reinterpret_cast<bf16x8*>(
      &ctx[((size_t)bb * NN + qbl * 256 + qloc) * 128 + gsw * 8]) = ch;
}

// ---------------------------------------------------------------------------
// Kernel 5: out = ctx @ W_o + b_o + X, async swizzled staging.
// ---------------------------------------------------------------------------
__global__ __launch_bounds__(256, 4) void out_gemm_kernel(const bf16_t* __restrict__ ctx,
                                                          const bf16_t* __restrict__ wot,
                                                          const float* __restrict__ bo,
                                                          const float* __restrict__ x0,
                                                          float* __restrict__ out) {
  __shared__ bf16_t lA[64 * 128];
  __shared__ bf16_t lB[64 * 128];
  const int m0 = blockIdx.x * 64;
  const int n0 = blockIdx.y * 64;
  const int tid = threadIdx.x;
  const int w = tid >> 6, lane = tid & 63;
  const int quad = lane >> 4, l15 = lane & 15;

#pragma unroll
  for (int i = 0; i < 4; i++) {
    int t = tid + i * 256;
    gld_lds16(&ctx[(size_t)m0 * 128 + t * 8], &lA[t * 8]);
    gld_lds16(&wot[(size_t)n0 * 128 + t * 8], &lB[t * 8]);
  }
  asm volatile("s_waitcnt vmcnt(0)" ::: "memory");
  __syncthreads();

  floatx4 zero4 = {0.f, 0.f, 0.f, 0.f};
  floatx4 acc[4];
#pragma unroll
  for (int nt = 0; nt < 4; nt++) acc[nt] = zero4;
#pragma unroll
  for (int kb = 0; kb < 4; kb++) {
    bf16x8 a = *reinterpret_cast<const bf16x8*>(&lA[(w * 16 + l15) * 128 + SW(l15, kb * 4 + quad)]);
#pragma unroll
    for (int nt = 0; nt < 4; nt++) {
      bf16x8 bfr = *reinterpret_cast<const bf16x8*>(&lB[(nt * 16 + l15) * 128 + SW(l15, kb * 4 + quad)]);
      acc[nt] = mfma16(a, bfr, acc[nt]);
    }
  }

#pragma unroll
  for (int nt = 0; nt < 4; nt++) {
    int n = n0 + nt * 16 + l15;
    float bias = bo[n];
#pragma unroll
    for (int r = 0; r < 4; r++) {
      size_t m = m0 + w * 16 + quad * 4 + r;
      out[m * 512 + n] = acc[nt][r] + bias + x0[m * 512 + n];
    }
  }
}

// ---------------------------------------------------------------------------
extern "C" void kernel_launch(void* const* d_in, const int* in_sizes, int n_in,
                              void* d_out, int out_size, void* d_ws, size_t ws_size,
                              hipStream_t stream) {
  const float* x  = (const float*)d_in[0];
  const float* wq = (const float*)d_in[1];
  const float* wk = (const float*)d_in[2];
  const float* wv = (const float*)d_in[3];
  const float* wo = (const float*)d_in[4];
  const float* bo = (const float*)d_in[5];
  float* out = (float*)d_out;

  char* ws = (char*)d_ws;
  // layout (bytes):
  //   0        Qb    4MB   [16384,128] bf16 (unswizzled)
  //   4M       Kb    4MB   (granule-swizzled)
  //   8M       Vt    4MB   [8][128][2048] bf16 (granule-swizzled)
  //   12M      Ctx   4MB   (granule-swizzled)
  //   16M      Wqkvt 384KB (granule-swizzled)
  //   16M+384K Wot   128KB (granule-swizzled)
  //   16.5M    Xb    16MB  (granule-swizzled; dead after qkv_gemm)
  //   16.5M    Op    16MB  [64 blk][4 split][256][128] bf16 (aliases Xb)
  //   48.5M    ml    256KB [64 blk][4 split][256] fp32
  bf16_t* Qb    = (bf16_t*)(ws);
  bf16_t* Kb    = (bf16_t*)(ws + 4194304);
  bf16_t* Vt    = (bf16_t*)(ws + 2 * 4194304);
  bf16_t* Ctx   = (bf16_t*)(ws + 3 * 4194304);
  bf16_t* Wqkvt = (bf16_t*)(ws + 4 * 4194304);
  bf16_t* Wot   = (bf16_t*)(ws + 4 * 4194304 + 393216);
  bf16_t* Xb    = (bf16_t*)(ws + 4 * 4194304 + 524288);
  bf16_t* Op    = (bf16_t*)(ws + 4 * 4194304 + 524288);   // aliases Xb
  float*  ml    = (float*)(ws + 4 * 4194304 + 524288 + 33554432);

  cast_x_kernel<<<4096, 256, 0, stream>>>(x, Xb);
  pack_w_kernel<<<1024, 256, 0, stream>>>(wq, wk, wv, wo, Wqkvt, Wot);
  qkv_gemm_kernel<<<dim3(128, 6), 256, 0, stream>>>(Xb, Wqkvt, Qb, Kb, Vt);
  attn_kernel<<<dim3(8, 8, SPLITS), 512, 0, stream>>>(Qb, Kb, Vt, Op, ml);
  merge_kernel<<<dim3(64, 16), 256, 0, stream>>>(Op, ml, Ctx);
  out_gemm_kernel<<<dim3(256, 8), 256, 0, stream>>>(Ctx, Wot, bo, x, out);
}

// Round 6
// 148.153 us; speedup vs baseline: 1.3369x; 1.3369x over previous
//
#include <hip/hip_runtime.h>

// Problem constants (B,N,D,U) = (8,2048,512,128)
#define BB 8
#define NN 2048
#define DD 512
#define UU 128
#define SPLITS 4
#define KSPLIT 512   // keys per split

typedef __bf16 bf16_t;
typedef __bf16 bf16x4 __attribute__((ext_vector_type(4)));
typedef __bf16 bf16x8 __attribute__((ext_vector_type(8)));
typedef float floatx4 __attribute__((ext_vector_type(4)));

__device__ __forceinline__ floatx4 mfma16(bf16x8 a, bf16x8 b, floatx4 c) {
  return __builtin_amdgcn_mfma_f32_16x16x32_bf16(a, b, c, 0, 0, 0);
}

// XOR swizzle on 16B granules: granule g of row r lives at column ((g^(r&7))*8).
#define SW(r, g) ((((g) ^ ((r) & 7)) * 8))

// async 16B global->LDS copy (dest must be wave-uniform base + lane*16)
__device__ __forceinline__ void gld_lds16(const bf16_t* g, bf16_t* l) {
  __builtin_amdgcn_global_load_lds(
      (const __attribute__((address_space(1))) unsigned int*)g,
      (__attribute__((address_space(3))) unsigned int*)l, 16, 0, 0);
}

// ---------------------------------------------------------------------------
// Kernel 1: cast X (fp32) -> bf16, stored granule-swizzled
// ---------------------------------------------------------------------------
__global__ __launch_bounds__(256) void cast_x_kernel(const float* __restrict__ x,
                                                     bf16_t* __restrict__ xb) {
  int G = blockIdx.x * 256 + threadIdx.x;   // global granule id (8 elems)
  int token = G >> 6;                        // 64 granules per 512-col row
  int g = G & 63;
  int dstg = (g & 56) | ((g & 7) ^ (token & 7));  // swizzle within 64-col chunk
  const float4* src = reinterpret_cast<const float4*>(x) + (size_t)G * 2;
  float4 a = src[0], b = src[1];
  bf16x8 o;
  o[0] = (bf16_t)a.x; o[1] = (bf16_t)a.y; o[2] = (bf16_t)a.z; o[3] = (bf16_t)a.w;
  o[4] = (bf16_t)b.x; o[5] = (bf16_t)b.y; o[6] = (bf16_t)b.z; o[7] = (bf16_t)b.w;
  *reinterpret_cast<bf16x8*>(&xb[(size_t)token * 512 + dstg * 8]) = o;
}

// ---------------------------------------------------------------------------
// Kernel 2: pack weights transposed bf16, granule-swizzled.
// ---------------------------------------------------------------------------
__global__ __launch_bounds__(256) void pack_w_kernel(const float* __restrict__ wq,
                                                     const float* __restrict__ wk,
                                                     const float* __restrict__ wv,
                                                     const float* __restrict__ wo,
                                                     bf16_t* __restrict__ wqkvt,
                                                     bf16_t* __restrict__ wot) {
  int gid = blockIdx.x * 256 + threadIdx.x;
  if (gid < 384 * 512) {
    int nrow = gid >> 9;
    int kdst = gid & 511;
    int ksrc = (kdst & ~56) | (((((kdst >> 3) & 7)) ^ (nrow & 7)) << 3);
    const float* src = (nrow < 128) ? wq : ((nrow < 256) ? wk : wv);
    int n = nrow & 127;
    wqkvt[gid] = (bf16_t)src[ksrc * 128 + n];
  } else {
    int g = gid - 384 * 512;
    int nrow = g >> 7;   // d index (row)
    int kdst = g & 127;  // u index (col)
    int ksrc = (kdst & ~56) | (((((kdst >> 3) & 7)) ^ (nrow & 7)) << 3);
    wot[g] = (bf16_t)wo[ksrc * 512 + nrow];
  }
}

// ---------------------------------------------------------------------------
// Kernel 3: QKV GEMM (128x64 tiles, async swizzled staging).
// 1D grid of 768 with XCD-chunked swizzle: each XCD gets 16 consecutive
// m-tiles x all 6 n-tiles, so each 128KB A-tile is fetched ~once per L2
// (A traffic ~96MB -> ~16MB).
// ---------------------------------------------------------------------------
__global__ __launch_bounds__(256, 4) void qkv_gemm_kernel(const bf16_t* __restrict__ xb,
                                                          const bf16_t* __restrict__ wqkvt,
                                                          bf16_t* __restrict__ Q,
                                                          bf16_t* __restrict__ K,
                                                          bf16_t* __restrict__ Vt) {
  __shared__ bf16_t lA[128 * 64];
  __shared__ bf16_t lB[64 * 64];
  const int lid = (blockIdx.x & 7) * 96 + (blockIdx.x >> 3);  // bijective, 768=8*96
  const int m0 = (lid / 6) * 128;
  const int n0 = (lid % 6) * 64;
  const int tid = threadIdx.x;
  const int w = tid >> 6, lane = tid & 63;
  const int quad = lane >> 4, l15 = lane & 15;

  floatx4 zero4 = {0.f, 0.f, 0.f, 0.f};
  floatx4 acc[2][4];
#pragma unroll
  for (int mi = 0; mi < 2; mi++)
#pragma unroll
    for (int nt = 0; nt < 4; nt++) acc[mi][nt] = zero4;

  for (int kc = 0; kc < 512; kc += 64) {
    __syncthreads();
#pragma unroll
    for (int i = 0; i < 4; i++) {
      int t = tid + i * 256;       // A granule 0..1023
      int r = t >> 3, g = t & 7;
      gld_lds16(&xb[(size_t)(m0 + r) * 512 + kc + g * 8], &lA[t * 8]);
    }
#pragma unroll
    for (int i = 0; i < 2; i++) {
      int t = tid + i * 256;       // B granule 0..511
      int r = t >> 3, g = t & 7;
      gld_lds16(&wqkvt[(size_t)(n0 + r) * 512 + kc + g * 8], &lB[t * 8]);
    }
    asm volatile("s_waitcnt vmcnt(0)" ::: "memory");
    __syncthreads();
#pragma unroll
    for (int kb = 0; kb < 2; kb++) {
      bf16x8 bfr[4];
#pragma unroll
      for (int nt = 0; nt < 4; nt++)
        bfr[nt] = *reinterpret_cast<const bf16x8*>(
            &lB[(nt * 16 + l15) * 64 + SW(l15, kb * 4 + quad)]);
#pragma unroll
      for (int mi = 0; mi < 2; mi++) {
        bf16x8 a = *reinterpret_cast<const bf16x8*>(
            &lA[(w * 32 + mi * 16 + l15) * 64 + SW(l15, kb * 4 + quad)]);
#pragma unroll
        for (int nt = 0; nt < 4; nt++)
          acc[mi][nt] = mfma16(a, bfr[nt], acc[mi][nt]);
      }
    }
  }

#pragma unroll
  for (int mi = 0; mi < 2; mi++)
#pragma unroll
    for (int nt = 0; nt < 4; nt++) {
      int n = n0 + nt * 16 + l15;
#pragma unroll
      for (int r = 0; r < 4; r++) {
        int token = m0 + w * 32 + mi * 16 + quad * 4 + r;
        bf16_t h = (bf16_t)acc[mi][nt][r];
        if (n < 128) {
          Q[(size_t)token * 128 + n] = h;
        } else if (n < 256) {
          int nk = n - 128;
          int nsw = (nk & ~56) | ((((nk >> 3) & 7) ^ (token & 7)) << 3);
          K[(size_t)token * 128 + nsw] = h;
        } else {
          int bidx = token >> 11;
          int t = token & 2047;
          int u = n - 256;
          int tsw = (t & ~56) | ((((t >> 3) & 7) ^ (u & 7)) << 3);
          Vt[((size_t)bidx * 128 + u) * 2048 + tsw] = h;
        }
      }
    }
}

// ---------------------------------------------------------------------------
// Kernel 4: split-K flash attention (round-1 structure: 256 thr, 128 q,
// double-buffered async staging, 2 blocks/CU) + XCD-chunked swizzle:
// the 16 qb-blocks sharing one (b,s) K/V split land on ONE XCD (64 resident
// blocks/XCD >= 16 => concurrent), so each 256KB K/V split is fetched ~once.
// ---------------------------------------------------------------------------
__global__ __launch_bounds__(256, 2) void attn_kernel(const bf16_t* __restrict__ Q,
                                                      const bf16_t* __restrict__ K,
                                                      const bf16_t* __restrict__ Vt,
                                                      bf16_t* __restrict__ Op,
                                                      float* __restrict__ ml) {
  __shared__ bf16_t lK[2][64 * 128];
  __shared__ bf16_t lV[2][128 * 64];
  __shared__ bf16_t lP[4][32 * 64];

  // 512 blocks: lid groups 16 qb-sharers contiguously; chunks of 64 per XCD.
  const int lid = (blockIdx.x & 7) * 64 + (blockIdx.x >> 3);
  const int qb = lid & 15;
  const int bs = lid >> 4;      // 0..31
  const int b = bs >> 2;
  const int s = bs & 3;
  const int tid = threadIdx.x;
  const int w = tid >> 6, lane = tid & 63;
  const int quad = lane >> 4, l15 = lane & 15;
  const float c = 0.08838834764831845f * 1.4426950408889634f;  // 1/sqrt(U)*log2e

  // Q fragments (B-operand of S^T)
  bf16x8 qf[2][4];
#pragma unroll
  for (int mt = 0; mt < 2; mt++) {
    const bf16_t* qrow =
        &Q[((size_t)b * NN + qb * 128 + w * 32 + mt * 16 + l15) * 128 + quad * 8];
#pragma unroll
    for (int kb = 0; kb < 4; kb++)
      qf[mt][kb] = *reinterpret_cast<const bf16x8*>(qrow + kb * 32);
  }

  float l_part[2] = {0.f, 0.f};
  floatx4 zero4 = {0.f, 0.f, 0.f, 0.f};
  floatx4 accO[2][8];
#pragma unroll
  for (int mt = 0; mt < 2; mt++)
#pragma unroll
    for (int ut = 0; ut < 8; ut++) accO[mt][ut] = zero4;

  bf16_t* pw = &lP[w][0];
  const int kt0 = s * KSPLIT;
  const bf16_t* kbase = &K[(size_t)b * NN * 128];
  const bf16_t* vbase = &Vt[(size_t)b * 128 * 2048];

  // prologue: stage tile 0 into buffer 0
  {
    const bf16_t* ksrc = kbase + (size_t)kt0 * 128;
#pragma unroll
    for (int i = 0; i < 4; i++) {
      int t = tid + i * 256;
      gld_lds16(ksrc + (size_t)t * 8, &lK[0][t * 8]);
    }
#pragma unroll
    for (int i = 0; i < 4; i++) {
      int t = tid + i * 256;
      int r = t >> 3, g = t & 7;
      gld_lds16(vbase + (size_t)r * 2048 + kt0 + g * 8, &lV[0][t * 8]);
    }
  }
  asm volatile("s_waitcnt vmcnt(0)" ::: "memory");
  __syncthreads();

  int cur = 0;
  for (int kt = kt0; kt < kt0 + KSPLIT; kt += 64) {
    // async stage of NEXT tile into the alternate buffer (no wait here)
    if (kt + 64 < kt0 + KSPLIT) {
      const int nxt = kt + 64;
      const bf16_t* ksrc = kbase + (size_t)nxt * 128;
#pragma unroll
      for (int i = 0; i < 4; i++) {
        int t = tid + i * 256;
        gld_lds16(ksrc + (size_t)t * 8, &lK[cur ^ 1][t * 8]);
      }
#pragma unroll
      for (int i = 0; i < 4; i++) {
        int t = tid + i * 256;
        int r = t >> 3, g = t & 7;
        gld_lds16(vbase + (size_t)r * 2048 + nxt + g * 8, &lV[cur ^ 1][t * 8]);
      }
    }

    // S^T[key][query]: A = K rows (LDS), B = Q rows (regs)
    floatx4 accS[4][2];
#pragma unroll
    for (int km = 0; km < 4; km++)
#pragma unroll
      for (int mt = 0; mt < 2; mt++) accS[km][mt] = zero4;
    __builtin_amdgcn_s_setprio(1);
#pragma unroll
    for (int kb = 0; kb < 4; kb++) {
#pragma unroll
      for (int km = 0; km < 4; km++) {
        bf16x8 kf = *reinterpret_cast<const bf16x8*>(
            &lK[cur][(km * 16 + l15) * 128 + SW(l15, kb * 4 + quad)]);
#pragma unroll
        for (int mt = 0; mt < 2; mt++)
          accS[km][mt] = mfma16(kf, qf[mt][kb], accS[km][mt]);
      }
    }
    __builtin_amdgcn_s_setprio(0);

    // p = exp2(c*s); accumulate l; pack P^T -> [q][key] LDS (b64, swizzled)
#pragma unroll
    for (int km = 0; km < 4; km++) {
#pragma unroll
      for (int mt = 0; mt < 2; mt++) {
        float p0 = __builtin_amdgcn_exp2f(accS[km][mt][0] * c);
        float p1 = __builtin_amdgcn_exp2f(accS[km][mt][1] * c);
        float p2 = __builtin_amdgcn_exp2f(accS[km][mt][2] * c);
        float p3 = __builtin_amdgcn_exp2f(accS[km][mt][3] * c);
        l_part[mt] += (p0 + p1) + (p2 + p3);
        bf16x4 pk;
        pk[0] = (bf16_t)p0; pk[1] = (bf16_t)p1; pk[2] = (bf16_t)p2; pk[3] = (bf16_t)p3;
        int row = mt * 16 + l15;
        int g = km * 2 + (quad >> 1);
        *reinterpret_cast<bf16x4*>(
            &pw[row * 64 + ((g ^ (row & 7)) * 8) + (quad & 1) * 4]) = pk;
      }
    }
    asm volatile("s_waitcnt lgkmcnt(0)" ::: "memory");

    // O += P V
    __builtin_amdgcn_s_setprio(1);
#pragma unroll
    for (int kb = 0; kb < 2; kb++) {
      bf16x8 pa[2];
#pragma unroll
      for (int mt = 0; mt < 2; mt++)
        pa[mt] = *reinterpret_cast<const bf16x8*>(
            &pw[(mt * 16 + l15) * 64 + SW(l15, kb * 4 + quad)]);
#pragma unroll
      for (int ut = 0; ut < 8; ut++) {
        bf16x8 bv = *reinterpret_cast<const bf16x8*>(
            &lV[cur][(ut * 16 + l15) * 64 + SW(l15, kb * 4 + quad)]);
#pragma unroll
        for (int mt = 0; mt < 2; mt++)
          accO[mt][ut] = mfma16(pa[mt], bv, accO[mt][ut]);
      }
    }
    __builtin_amdgcn_s_setprio(0);

    // drain next-tile loads (issued a full compute-phase ago) + one barrier
    asm volatile("s_waitcnt vmcnt(0)" ::: "memory");
    __syncthreads();
    cur ^= 1;
  }

#pragma unroll
  for (int mt = 0; mt < 2; mt++) {
    float v = l_part[mt];
    v += __shfl_xor(v, 16);
    v += __shfl_xor(v, 32);
    l_part[mt] = v;
  }

  size_t base = ((size_t)(b * 16 + qb) * SPLITS + s);
  bf16_t* op = Op + base * (128 * 128);
  float* mlp = ml + base * 128;
#pragma unroll
  for (int mt = 0; mt < 2; mt++)
#pragma unroll
    for (int ut = 0; ut < 8; ut++)
#pragma unroll
      for (int r = 0; r < 4; r++)
        op[(w * 32 + mt * 16 + quad * 4 + r) * 128 + ut * 16 + l15] =
            (bf16_t)accO[mt][ut][r];
  if (quad == 0) {
#pragma unroll
    for (int mt = 0; mt < 2; mt++) mlp[w * 32 + mt * 16 + l15] = l_part[mt];
  }
}

// ---------------------------------------------------------------------------
// Kernel 4b: merge split-K partials -> ctx bf16, granule-swizzled.
// Fully coalesced: one 16B granule per thread, lanes sweep granules.
// Grid (128 blk, 8 q-groups); block = 16 q x 16 granules.
// ---------------------------------------------------------------------------
__global__ __launch_bounds__(256) void merge_kernel(const bf16_t* __restrict__ Op,
                                                    const float* __restrict__ ml,
                                                    bf16_t* __restrict__ ctx) {
  const int blk = blockIdx.x;                             // b*16 + qb
  const int qloc = blockIdx.y * 16 + (threadIdx.x >> 4);  // 0..127
  const int g = threadIdx.x & 15;                         // granule 0..15

  float L = 0.f;
  float o[8];
#pragma unroll
  for (int j = 0; j < 8; j++) o[j] = 0.f;
#pragma unroll
  for (int s = 0; s < SPLITS; s++) {
    size_t e = (size_t)blk * SPLITS + s;
    L += ml[e * 128 + qloc];
    bf16x8 ch = *reinterpret_cast<const bf16x8*>(&Op[(e * 128 + qloc) * 128 + g * 8]);
#pragma unroll
    for (int j = 0; j < 8; j++) o[j] += (float)ch[j];
  }
  float inv = 1.0f / L;
  int gsw = (g & 8) | ((g & 7) ^ (qloc & 7));
  bf16x8 ch;
#pragma unroll
  for (int j = 0; j < 8; j++) ch[j] = (bf16_t)(o[j] * inv);
  const int bb = blk >> 4, qbl = blk & 15;
  *reinterpret_cast<bf16x8*>(
      &ctx[((size_t)bb * NN + qbl * 128 + qloc) * 128 + gsw * 8]) = ch;
}

// ---------------------------------------------------------------------------
// Kernel 5: out = ctx @ W_o + b_o + X, async swizzled staging.
// 1D grid of 2048, XCD-chunked: 32 consecutive m-tiles x 8 n per XCD ->
// ctx fetched ~once per L2 (32MB -> ~4MB).
// ---------------------------------------------------------------------------
__global__ __launch_bounds__(256, 4) void out_gemm_kernel(const bf16_t* __restrict__ ctx,
                                                          const bf16_t* __restrict__ wot,
                                                          const float* __restrict__ bo,
                                                          const float* __restrict__ x0,
                                                          float* __restrict__ out) {
  __shared__ bf16_t lA[64 * 128];
  __shared__ bf16_t lB[64 * 128];
  const int lid = (blockIdx.x & 7) * 256 + (blockIdx.x >> 3);  // 2048 = 8*256
  const int m0 = (lid >> 3) * 64;
  const int n0 = (lid & 7) * 64;
  const int tid = threadIdx.x;
  const int w = tid >> 6, lane = tid & 63;
  const int quad = lane >> 4, l15 = lane & 15;

#pragma unroll
  for (int i = 0; i < 4; i++) {
    int t = tid + i * 256;
    gld_lds16(&ctx[(size_t)m0 * 128 + t * 8], &lA[t * 8]);
    gld_lds16(&wot[(size_t)n0 * 128 + t * 8], &lB[t * 8]);
  }
  asm volatile("s_waitcnt vmcnt(0)" ::: "memory");
  __syncthreads();

  floatx4 zero4 = {0.f, 0.f, 0.f, 0.f};
  floatx4 acc[4];
#pragma unroll
  for (int nt = 0; nt < 4; nt++) acc[nt] = zero4;
#pragma unroll
  for (int kb = 0; kb < 4; kb++) {
    bf16x8 a = *reinterpret_cast<const bf16x8*>(&lA[(w * 16 + l15) * 128 + SW(l15, kb * 4 + quad)]);
#pragma unroll
    for (int nt = 0; nt < 4; nt++) {
      bf16x8 bfr = *reinterpret_cast<const bf16x8*>(&lB[(nt * 16 + l15) * 128 + SW(l15, kb * 4 + quad)]);
      acc[nt] = mfma16(a, bfr, acc[nt]);
    }
  }

#pragma unroll
  for (int nt = 0; nt < 4; nt++) {
    int n = n0 + nt * 16 + l15;
    float bias = bo[n];
#pragma unroll
    for (int r = 0; r < 4; r++) {
      size_t m = m0 + w * 16 + quad * 4 + r;
      out[m * 512 + n] = acc[nt][r] + bias + x0[m * 512 + n];
    }
  }
}

// ---------------------------------------------------------------------------
extern "C" void kernel_launch(void* const* d_in, const int* in_sizes, int n_in,
                              void* d_out, int out_size, void* d_ws, size_t ws_size,
                              hipStream_t stream) {
  const float* x  = (const float*)d_in[0];
  const float* wq = (const float*)d_in[1];
  const float* wk = (const float*)d_in[2];
  const float* wv = (const float*)d_in[3];
  const float* wo = (const float*)d_in[4];
  const float* bo = (const float*)d_in[5];
  float* out = (float*)d_out;

  char* ws = (char*)d_ws;
  // layout (bytes):
  //   0        Qb    4MB   [16384,128] bf16 (unswizzled)
  //   4M       Kb    4MB   (granule-swizzled)
  //   8M       Vt    4MB   [8][128][2048] bf16 (granule-swizzled)
  //   12M      Ctx   4MB   (granule-swizzled)
  //   16M      Wqkvt 384KB (granule-swizzled)
  //   16M+384K Wot   128KB (granule-swizzled)
  //   16.5M    Xb    16MB  (granule-swizzled; dead after qkv_gemm)
  //   16.5M    Op    16MB  [128 blk][4 split][128][128] bf16 (aliases Xb)
  //   48.5M    ml    256KB [128 blk][4 split][128] fp32
  bf16_t* Qb    = (bf16_t*)(ws);
  bf16_t* Kb    = (bf16_t*)(ws + 4194304);
  bf16_t* Vt    = (bf16_t*)(ws + 2 * 4194304);
  bf16_t* Ctx   = (bf16_t*)(ws + 3 * 4194304);
  bf16_t* Wqkvt = (bf16_t*)(ws + 4 * 4194304);
  bf16_t* Wot   = (bf16_t*)(ws + 4 * 4194304 + 393216);
  bf16_t* Xb    = (bf16_t*)(ws + 4 * 4194304 + 524288);
  bf16_t* Op    = (bf16_t*)(ws + 4 * 4194304 + 524288);   // aliases Xb
  float*  ml    = (float*)(ws + 4 * 4194304 + 524288 + 33554432);

  cast_x_kernel<<<4096, 256, 0, stream>>>(x, Xb);
  pack_w_kernel<<<1024, 256, 0, stream>>>(wq, wk, wv, wo, Wqkvt, Wot);
  qkv_gemm_kernel<<<768, 256, 0, stream>>>(Xb, Wqkvt, Qb, Kb, Vt);
  attn_kernel<<<512, 256, 0, stream>>>(Qb, Kb, Vt, Op, ml);
  merge_kernel<<<dim3(128, 8), 256, 0, stream>>>(Op, ml, Ctx);
  out_gemm_kernel<<<2048, 256, 0, stream>>>(Ctx, Wot, bo, x, out);
}

// Round 7
// 146.831 us; speedup vs baseline: 1.3489x; 1.0090x over previous
//
#include <hip/hip_runtime.h>

// Problem constants (B,N,D,U) = (8,2048,512,128)
#define BB 8
#define NN 2048
#define DD 512
#define UU 128
#define SPLITS 4
#define KSPLIT 512   // keys per split

typedef __bf16 bf16_t;
typedef __bf16 bf16x4 __attribute__((ext_vector_type(4)));
typedef __bf16 bf16x8 __attribute__((ext_vector_type(8)));
typedef float floatx4 __attribute__((ext_vector_type(4)));
typedef float floatx16 __attribute__((ext_vector_type(16)));

__device__ __forceinline__ floatx4 mfma16(bf16x8 a, bf16x8 b, floatx4 c) {
  return __builtin_amdgcn_mfma_f32_16x16x32_bf16(a, b, c, 0, 0, 0);
}
__device__ __forceinline__ floatx16 mfma32(bf16x8 a, bf16x8 b, floatx16 c) {
  return __builtin_amdgcn_mfma_f32_32x32x16_bf16(a, b, c, 0, 0, 0);
}

// pack two f32 -> one u32 of 2 bf16 (lo = a, hi = b)
__device__ __forceinline__ unsigned int pk2(float a, float b) {
  union { bf16_t x[2]; unsigned int u; } t;
  t.x[0] = (bf16_t)a; t.x[1] = (bf16_t)b;
  return t.u;
}

// XOR swizzle on 16B granules: granule g of row r lives at column ((g^(r&7))*8).
#define SW(r, g) ((((g) ^ ((r) & 7)) * 8))

// async 16B global->LDS copy (dest must be wave-uniform base + lane*16)
__device__ __forceinline__ void gld_lds16(const bf16_t* g, bf16_t* l) {
  __builtin_amdgcn_global_load_lds(
      (const __attribute__((address_space(1))) unsigned int*)g,
      (__attribute__((address_space(3))) unsigned int*)l, 16, 0, 0);
}

// ---------------------------------------------------------------------------
// Kernel 1: cast X (fp32) -> bf16, stored granule-swizzled
// ---------------------------------------------------------------------------
__global__ __launch_bounds__(256) void cast_x_kernel(const float* __restrict__ x,
                                                     bf16_t* __restrict__ xb) {
  int G = blockIdx.x * 256 + threadIdx.x;   // global granule id (8 elems)
  int token = G >> 6;                        // 64 granules per 512-col row
  int g = G & 63;
  int dstg = (g & 56) | ((g & 7) ^ (token & 7));  // swizzle within 64-col chunk
  const float4* src = reinterpret_cast<const float4*>(x) + (size_t)G * 2;
  float4 a = src[0], b = src[1];
  bf16x8 o;
  o[0] = (bf16_t)a.x; o[1] = (bf16_t)a.y; o[2] = (bf16_t)a.z; o[3] = (bf16_t)a.w;
  o[4] = (bf16_t)b.x; o[5] = (bf16_t)b.y; o[6] = (bf16_t)b.z; o[7] = (bf16_t)b.w;
  *reinterpret_cast<bf16x8*>(&xb[(size_t)token * 512 + dstg * 8]) = o;
}

// ---------------------------------------------------------------------------
// Kernel 2: pack weights transposed bf16, granule-swizzled.
// ---------------------------------------------------------------------------
__global__ __launch_bounds__(256) void pack_w_kernel(const float* __restrict__ wq,
                                                     const float* __restrict__ wk,
                                                     const float* __restrict__ wv,
                                                     const float* __restrict__ wo,
                                                     bf16_t* __restrict__ wqkvt,
                                                     bf16_t* __restrict__ wot) {
  int gid = blockIdx.x * 256 + threadIdx.x;
  if (gid < 384 * 512) {
    int nrow = gid >> 9;
    int kdst = gid & 511;
    int ksrc = (kdst & ~56) | (((((kdst >> 3) & 7)) ^ (nrow & 7)) << 3);
    const float* src = (nrow < 128) ? wq : ((nrow < 256) ? wk : wv);
    int n = nrow & 127;
    wqkvt[gid] = (bf16_t)src[ksrc * 128 + n];
  } else {
    int g = gid - 384 * 512;
    int nrow = g >> 7;   // d index (row)
    int kdst = g & 127;  // u index (col)
    int ksrc = (kdst & ~56) | (((((kdst >> 3) & 7)) ^ (nrow & 7)) << 3);
    wot[g] = (bf16_t)wo[ksrc * 512 + nrow];
  }
}

// ---------------------------------------------------------------------------
// Kernel 3: QKV GEMM (128x64 tiles, async swizzled staging).
// ---------------------------------------------------------------------------
__global__ __launch_bounds__(256, 4) void qkv_gemm_kernel(const bf16_t* __restrict__ xb,
                                                          const bf16_t* __restrict__ wqkvt,
                                                          bf16_t* __restrict__ Q,
                                                          bf16_t* __restrict__ K,
                                                          bf16_t* __restrict__ Vt) {
  __shared__ bf16_t lA[128 * 64];
  __shared__ bf16_t lB[64 * 64];
  const int lid = (blockIdx.x & 7) * 96 + (blockIdx.x >> 3);  // bijective, 768=8*96
  const int m0 = (lid / 6) * 128;
  const int n0 = (lid % 6) * 64;
  const int tid = threadIdx.x;
  const int w = tid >> 6, lane = tid & 63;
  const int quad = lane >> 4, l15 = lane & 15;

  floatx4 zero4 = {0.f, 0.f, 0.f, 0.f};
  floatx4 acc[2][4];
#pragma unroll
  for (int mi = 0; mi < 2; mi++)
#pragma unroll
    for (int nt = 0; nt < 4; nt++) acc[mi][nt] = zero4;

  for (int kc = 0; kc < 512; kc += 64) {
    __syncthreads();
#pragma unroll
    for (int i = 0; i < 4; i++) {
      int t = tid + i * 256;       // A granule 0..1023
      int r = t >> 3, g = t & 7;
      gld_lds16(&xb[(size_t)(m0 + r) * 512 + kc + g * 8], &lA[t * 8]);
    }
#pragma unroll
    for (int i = 0; i < 2; i++) {
      int t = tid + i * 256;       // B granule 0..511
      int r = t >> 3, g = t & 7;
      gld_lds16(&wqkvt[(size_t)(n0 + r) * 512 + kc + g * 8], &lB[t * 8]);
    }
    asm volatile("s_waitcnt vmcnt(0)" ::: "memory");
    __syncthreads();
#pragma unroll
    for (int kb = 0; kb < 2; kb++) {
      bf16x8 bfr[4];
#pragma unroll
      for (int nt = 0; nt < 4; nt++)
        bfr[nt] = *reinterpret_cast<const bf16x8*>(
            &lB[(nt * 16 + l15) * 64 + SW(l15, kb * 4 + quad)]);
#pragma unroll
      for (int mi = 0; mi < 2; mi++) {
        bf16x8 a = *reinterpret_cast<const bf16x8*>(
            &lA[(w * 32 + mi * 16 + l15) * 64 + SW(l15, kb * 4 + quad)]);
#pragma unroll
        for (int nt = 0; nt < 4; nt++)
          acc[mi][nt] = mfma16(a, bfr[nt], acc[mi][nt]);
      }
    }
  }

#pragma unroll
  for (int mi = 0; mi < 2; mi++)
#pragma unroll
    for (int nt = 0; nt < 4; nt++) {
      int n = n0 + nt * 16 + l15;
#pragma unroll
      for (int r = 0; r < 4; r++) {
        int token = m0 + w * 32 + mi * 16 + quad * 4 + r;
        bf16_t h = (bf16_t)acc[mi][nt][r];
        if (n < 128) {
          Q[(size_t)token * 128 + n] = h;
        } else if (n < 256) {
          int nk = n - 128;
          int nsw = (nk & ~56) | ((((nk >> 3) & 7) ^ (token & 7)) << 3);
          K[(size_t)token * 128 + nsw] = h;
        } else {
          int bidx = token >> 11;
          int t = token & 2047;
          int u = n - 256;
          int tsw = (t & ~56) | ((((t >> 3) & 7) ^ (u & 7)) << 3);
          Vt[((size_t)bidx * 128 + u) * 2048 + tsw] = h;
        }
      }
    }
}

// ---------------------------------------------------------------------------
// Kernel 4: split-K flash attention, 32x32x16 MFMA core, in-register P.
// Block: 256 thr / 4 waves / 128 queries; KVBLK=64; K,V double-buffered.
// Per wave: lane (q=l&31, h=l>>5). QK^T: A=K rows (32x16 frags from LDS),
// B=Q (regs) -> S^T[key][q] in 2 floatx16. Softmax in regs; P^T transposed
// to PV A-fragments via pk2 + one __shfl_xor(.,32) half-swap (no P LDS).
// LDS: 2*16K (K) + 2*16K (V) = 64KB -> 2 blocks/CU.
// ---------------------------------------------------------------------------
__global__ __launch_bounds__(256, 2) void attn_kernel(const bf16_t* __restrict__ Q,
                                                      const bf16_t* __restrict__ K,
                                                      const bf16_t* __restrict__ Vt,
                                                      bf16_t* __restrict__ Op,
                                                      float* __restrict__ ml) {
  __shared__ bf16_t lK[2][64 * 128];
  __shared__ bf16_t lV[2][128 * 64];

  const int lid = (blockIdx.x & 7) * 64 + (blockIdx.x >> 3);
  const int qb = lid & 15;
  const int bs = lid >> 4;      // 0..31
  const int b = bs >> 2;
  const int s = bs & 3;
  const int tid = threadIdx.x;
  const int w = tid >> 6, lane = tid & 63;
  const int l31 = lane & 31, h = lane >> 5;
  const float c = 0.08838834764831845f * 1.4426950408889634f;  // 1/sqrt(U)*log2e

  // Q fragments (B-operand of S^T): lane owns query column q = w*32+l31,
  // k = kb*16 + h*8 + {0..7}
  bf16x8 qf[8];
  {
    const bf16_t* qrow =
        &Q[((size_t)b * NN + qb * 128 + w * 32 + l31) * 128 + h * 8];
#pragma unroll
    for (int kb = 0; kb < 8; kb++)
      qf[kb] = *reinterpret_cast<const bf16x8*>(qrow + kb * 16);
  }

  float l_part = 0.f;
  floatx16 accO[4];
#pragma unroll
  for (int ut = 0; ut < 4; ut++)
#pragma unroll
    for (int i = 0; i < 16; i++) accO[ut][i] = 0.f;

  const int kt0 = s * KSPLIT;
  const bf16_t* kbase = &K[(size_t)b * NN * 128];
  const bf16_t* vbase = &Vt[(size_t)b * 128 * 2048];

  // prologue: stage tile 0 into buffer 0
  {
    const bf16_t* ksrc = kbase + (size_t)kt0 * 128;
#pragma unroll
    for (int i = 0; i < 4; i++) {
      int t = tid + i * 256;
      gld_lds16(ksrc + (size_t)t * 8, &lK[0][t * 8]);
    }
#pragma unroll
    for (int i = 0; i < 4; i++) {
      int t = tid + i * 256;
      int r = t >> 3, g = t & 7;
      gld_lds16(vbase + (size_t)r * 2048 + kt0 + g * 8, &lV[0][t * 8]);
    }
  }
  asm volatile("s_waitcnt vmcnt(0)" ::: "memory");
  __syncthreads();

  int cur = 0;
  for (int kt = kt0; kt < kt0 + KSPLIT; kt += 64) {
    // async stage of NEXT tile into the alternate buffer (no wait here)
    if (kt + 64 < kt0 + KSPLIT) {
      const int nxt = kt + 64;
      const bf16_t* ksrc = kbase + (size_t)nxt * 128;
#pragma unroll
      for (int i = 0; i < 4; i++) {
        int t = tid + i * 256;
        gld_lds16(ksrc + (size_t)t * 8, &lK[cur ^ 1][t * 8]);
      }
#pragma unroll
      for (int i = 0; i < 4; i++) {
        int t = tid + i * 256;
        int r = t >> 3, g = t & 7;
        gld_lds16(vbase + (size_t)r * 2048 + nxt + g * 8, &lV[cur ^ 1][t * 8]);
      }
    }

    // S^T = K . Q^T via 32x32x16: A row = key (l31 within km*32), k = h*8+e
    floatx16 accS[2];
#pragma unroll
    for (int km = 0; km < 2; km++)
#pragma unroll
      for (int i = 0; i < 16; i++) accS[km][i] = 0.f;

    __builtin_amdgcn_s_setprio(1);
#pragma unroll
    for (int kb = 0; kb < 8; kb++) {
#pragma unroll
      for (int km = 0; km < 2; km++) {
        int r = km * 32 + l31;
        bf16x8 kf = *reinterpret_cast<const bf16x8*>(
            &lK[cur][r * 128 + SW(r, kb * 2 + h)]);
        accS[km] = mfma32(kf, qf[kb], accS[km]);
      }
    }
    __builtin_amdgcn_s_setprio(0);

    // softmax + in-register transpose to PV A-fragments.
    // D layout: key_local = (i&3)+8*(i>>2)+4h (+32km), col q = l31.
    // PV A-frag elem j (k-step ks=2km+s2): tok = ks*16 + h*8 + j; source
    // reg i = (j&3)+4*(2*s2+h), source half = j>>2  ->  one half-swap.
    bf16x8 pa[4];
#pragma unroll
    for (int km = 0; km < 2; km++) {
      float p[16];
#pragma unroll
      for (int i = 0; i < 16; i++) {
        p[i] = __builtin_amdgcn_exp2f(accS[km][i] * c);
        l_part += p[i];
      }
#pragma unroll
      for (int s2 = 0; s2 < 2; s2++) {
        unsigned int w00 = pk2(p[8 * s2 + 0], p[8 * s2 + 1]);  // P0 regs 8s2+0..3
        unsigned int w01 = pk2(p[8 * s2 + 2], p[8 * s2 + 3]);
        unsigned int w10 = pk2(p[8 * s2 + 4], p[8 * s2 + 5]);  // P1 regs 8s2+4..7
        unsigned int w11 = pk2(p[8 * s2 + 6], p[8 * s2 + 7]);
        // lane (q,0) must send its P1; lane (q,1) its P0
        unsigned int s0 = h ? w00 : w10;
        unsigned int s1 = h ? w01 : w11;
        unsigned int r0 = __shfl_xor(s0, 32);
        unsigned int r1 = __shfl_xor(s1, 32);
        union { unsigned int u[4]; bf16x8 v; } af;
        af.u[0] = h ? r0 : w00;   // elems 0..3 (src half 0)
        af.u[1] = h ? r1 : w01;
        af.u[2] = h ? w10 : r0;   // elems 4..7 (src half 1)
        af.u[3] = h ? w11 : r1;
        pa[km * 2 + s2] = af.v;
      }
    }

    // O += P V : A = pa (rows q), B = V rows (k=tok, col u = l31)
    __builtin_amdgcn_s_setprio(1);
#pragma unroll
    for (int ut = 0; ut < 4; ut++) {
#pragma unroll
      for (int ks = 0; ks < 4; ks++) {
        int ur = ut * 32 + l31;
        bf16x8 vf = *reinterpret_cast<const bf16x8*>(
            &lV[cur][ur * 64 + SW(ur, ks * 2 + h)]);
        accO[ut] = mfma32(pa[ks], vf, accO[ut]);
      }
    }
    __builtin_amdgcn_s_setprio(0);

    // drain next-tile loads (issued a full compute-phase ago) + one barrier
    asm volatile("s_waitcnt vmcnt(0)" ::: "memory");
    __syncthreads();
    cur ^= 1;
  }

  l_part += __shfl_xor(l_part, 32);

  size_t base = ((size_t)(b * 16 + qb) * SPLITS + s);
  bf16_t* op = Op + base * (128 * 128);
#pragma unroll
  for (int ut = 0; ut < 4; ut++)
#pragma unroll
    for (int i = 0; i < 16; i++) {
      int qr = w * 32 + (i & 3) + 8 * (i >> 2) + 4 * h;
      op[qr * 128 + ut * 32 + l31] = (bf16_t)accO[ut][i];
    }
  if (h == 0) ml[base * 128 + w * 32 + l31] = l_part;
}

// ---------------------------------------------------------------------------
// Kernel 4b: merge split-K partials -> ctx bf16, granule-swizzled.
// Fully coalesced: one 16B granule per thread, lanes sweep granules.
// Grid (128 blk, 8 q-groups); block = 16 q x 16 granules.
// ---------------------------------------------------------------------------
__global__ __launch_bounds__(256) void merge_kernel(const bf16_t* __restrict__ Op,
                                                    const float* __restrict__ ml,
                                                    bf16_t* __restrict__ ctx) {
  const int blk = blockIdx.x;                             // b*16 + qb
  const int qloc = blockIdx.y * 16 + (threadIdx.x >> 4);  // 0..127
  const int g = threadIdx.x & 15;                         // granule 0..15

  float L = 0.f;
  float o[8];
#pragma unroll
  for (int j = 0; j < 8; j++) o[j] = 0.f;
#pragma unroll
  for (int s = 0; s < SPLITS; s++) {
    size_t e = (size_t)blk * SPLITS + s;
    L += ml[e * 128 + qloc];
    bf16x8 ch = *reinterpret_cast<const bf16x8*>(&Op[(e * 128 + qloc) * 128 + g * 8]);
#pragma unroll
    for (int j = 0; j < 8; j++) o[j] += (float)ch[j];
  }
  float inv = 1.0f / L;
  int gsw = (g & 8) | ((g & 7) ^ (qloc & 7));
  bf16x8 ch;
#pragma unroll
  for (int j = 0; j < 8; j++) ch[j] = (bf16_t)(o[j] * inv);
  const int bb = blk >> 4, qbl = blk & 15;
  *reinterpret_cast<bf16x8*>(
      &ctx[((size_t)bb * NN + qbl * 128 + qloc) * 128 + gsw * 8]) = ch;
}

// ---------------------------------------------------------------------------
// Kernel 5: out = ctx @ W_o + b_o + X, async swizzled staging.
// ---------------------------------------------------------------------------
__global__ __launch_bounds__(256, 4) void out_gemm_kernel(const bf16_t* __restrict__ ctx,
                                                          const bf16_t* __restrict__ wot,
                                                          const float* __restrict__ bo,
                                                          const float* __restrict__ x0,
                                                          float* __restrict__ out) {
  __shared__ bf16_t lA[64 * 128];
  __shared__ bf16_t lB[64 * 128];
  const int lid = (blockIdx.x & 7) * 256 + (blockIdx.x >> 3);  // 2048 = 8*256
  const int m0 = (lid >> 3) * 64;
  const int n0 = (lid & 7) * 64;
  const int tid = threadIdx.x;
  const int w = tid >> 6, lane = tid & 63;
  const int quad = lane >> 4, l15 = lane & 15;

#pragma unroll
  for (int i = 0; i < 4; i++) {
    int t = tid + i * 256;
    gld_lds16(&ctx[(size_t)m0 * 128 + t * 8], &lA[t * 8]);
    gld_lds16(&wot[(size_t)n0 * 128 + t * 8], &lB[t * 8]);
  }
  asm volatile("s_waitcnt vmcnt(0)" ::: "memory");
  __syncthreads();

  floatx4 zero4 = {0.f, 0.f, 0.f, 0.f};
  floatx4 acc[4];
#pragma unroll
  for (int nt = 0; nt < 4; nt++) acc[nt] = zero4;
#pragma unroll
  for (int kb = 0; kb < 4; kb++) {
    bf16x8 a = *reinterpret_cast<const bf16x8*>(&lA[(w * 16 + l15) * 128 + SW(l15, kb * 4 + quad)]);
#pragma unroll
    for (int nt = 0; nt < 4; nt++) {
      bf16x8 bfr = *reinterpret_cast<const bf16x8*>(&lB[(nt * 16 + l15) * 128 + SW(l15, kb * 4 + quad)]);
      acc[nt] = mfma16(a, bfr, acc[nt]);
    }
  }

#pragma unroll
  for (int nt = 0; nt < 4; nt++) {
    int n = n0 + nt * 16 + l15;
    float bias = bo[n];
#pragma unroll
    for (int r = 0; r < 4; r++) {
      size_t m = m0 + w * 16 + quad * 4 + r;
      out[m * 512 + n] = acc[nt][r] + bias + x0[m * 512 + n];
    }
  }
}

// ---------------------------------------------------------------------------
extern "C" void kernel_launch(void* const* d_in, const int* in_sizes, int n_in,
                              void* d_out, int out_size, void* d_ws, size_t ws_size,
                              hipStream_t stream) {
  const float* x  = (const float*)d_in[0];
  const float* wq = (const float*)d_in[1];
  const float* wk = (const float*)d_in[2];
  const float* wv = (const float*)d_in[3];
  const float* wo = (const float*)d_in[4];
  const float* bo = (const float*)d_in[5];
  float* out = (float*)d_out;

  char* ws = (char*)d_ws;
  // layout (bytes):
  //   0        Qb    4MB   [16384,128] bf16 (unswizzled)
  //   4M       Kb    4MB   (granule-swizzled)
  //   8M       Vt    4MB   [8][128][2048] bf16 (granule-swizzled)
  //   12M      Ctx   4MB   (granule-swizzled)
  //   16M      Wqkvt 384KB (granule-swizzled)
  //   16M+384K Wot   128KB (granule-swizzled)
  //   16.5M    Xb    16MB  (granule-swizzled; dead after qkv_gemm)
  //   16.5M    Op    16MB  [128 blk][4 split][128][128] bf16 (aliases Xb)
  //   48.5M    ml    256KB [128 blk][4 split][128] fp32
  bf16_t* Qb    = (bf16_t*)(ws);
  bf16_t* Kb    = (bf16_t*)(ws + 4194304);
  bf16_t* Vt    = (bf16_t*)(ws + 2 * 4194304);
  bf16_t* Ctx   = (bf16_t*)(ws + 3 * 4194304);
  bf16_t* Wqkvt = (bf16_t*)(ws + 4 * 4194304);
  bf16_t* Wot   = (bf16_t*)(ws + 4 * 4194304 + 393216);
  bf16_t* Xb    = (bf16_t*)(ws + 4 * 4194304 + 524288);
  bf16_t* Op    = (bf16_t*)(ws + 4 * 4194304 + 524288);   // aliases Xb
  float*  ml    = (float*)(ws + 4 * 4194304 + 524288 + 33554432);

  cast_x_kernel<<<4096, 256, 0, stream>>>(x, Xb);
  pack_w_kernel<<<1024, 256, 0, stream>>>(wq, wk, wv, wo, Wqkvt, Wot);
  qkv_gemm_kernel<<<768, 256, 0, stream>>>(Xb, Wqkvt, Qb, Kb, Vt);
  attn_kernel<<<512, 256, 0, stream>>>(Qb, Kb, Vt, Op, ml);
  merge_kernel<<<dim3(128, 8), 256, 0, stream>>>(Op, ml, Ctx);
  out_gemm_kernel<<<2048, 256, 0, stream>>>(Ctx, Wot, bo, x, out);
}

// Round 10
// 143.657 us; speedup vs baseline: 1.3787x; 1.0221x over previous
//
#include <hip/hip_runtime.h>

// Problem constants (B,N,D,U) = (8,2048,512,128)
#define BB 8
#define NN 2048
#define DD 512
#define UU 128
#define SPLITS 4
#define KSPLIT 512   // keys per split

typedef __bf16 bf16_t;
typedef __bf16 bf16x4 __attribute__((ext_vector_type(4)));
typedef __bf16 bf16x8 __attribute__((ext_vector_type(8)));
typedef float floatx4 __attribute__((ext_vector_type(4)));
typedef float floatx16 __attribute__((ext_vector_type(16)));

__device__ __forceinline__ floatx4 mfma16(bf16x8 a, bf16x8 b, floatx4 c) {
  return __builtin_amdgcn_mfma_f32_16x16x32_bf16(a, b, c, 0, 0, 0);
}
__device__ __forceinline__ floatx16 mfma32(bf16x8 a, bf16x8 b, floatx16 c) {
  return __builtin_amdgcn_mfma_f32_32x32x16_bf16(a, b, c, 0, 0, 0);
}

// pack two f32 -> one u32 of 2 bf16 (lo = a, hi = b)
__device__ __forceinline__ unsigned int pk2(float a, float b) {
  union { bf16_t x[2]; unsigned int u; } t;
  t.x[0] = (bf16_t)a; t.x[1] = (bf16_t)b;
  return t.u;
}

// XOR swizzle on 16B granules: granule g of row r lives at column ((g^(r&7))*8).
#define SW(r, g) ((((g) ^ ((r) & 7)) * 8))

// async 16B global->LDS copy (dest must be wave-uniform base + lane*16)
__device__ __forceinline__ void gld_lds16(const bf16_t* g, bf16_t* l) {
  __builtin_amdgcn_global_load_lds(
      (const __attribute__((address_space(1))) unsigned int*)g,
      (__attribute__((address_space(3))) unsigned int*)l, 16, 0, 0);
}

// ---------------------------------------------------------------------------
// Kernel 1: prep = cast X (fp32)->bf16 swizzled  +  pack weights (fused).
// Blocks 0..4095: cast (one 16B granule/thread). Blocks 4096..5119: pack.
// ---------------------------------------------------------------------------
__global__ __launch_bounds__(256) void prep_kernel(const float* __restrict__ x,
                                                   const float* __restrict__ wq,
                                                   const float* __restrict__ wk,
                                                   const float* __restrict__ wv,
                                                   const float* __restrict__ wo,
                                                   bf16_t* __restrict__ xb,
                                                   bf16_t* __restrict__ wqkvt,
                                                   bf16_t* __restrict__ wot) {
  if (blockIdx.x < 4096) {
    int G = blockIdx.x * 256 + threadIdx.x;   // global granule id (8 elems)
    int token = G >> 6;                        // 64 granules per 512-col row
    int g = G & 63;
    int dstg = (g & 56) | ((g & 7) ^ (token & 7));  // swizzle within 64-col chunk
    const float4* src = reinterpret_cast<const float4*>(x) + (size_t)G * 2;
    float4 a = src[0], b = src[1];
    bf16x8 o;
    o[0] = (bf16_t)a.x; o[1] = (bf16_t)a.y; o[2] = (bf16_t)a.z; o[3] = (bf16_t)a.w;
    o[4] = (bf16_t)b.x; o[5] = (bf16_t)b.y; o[6] = (bf16_t)b.z; o[7] = (bf16_t)b.w;
    *reinterpret_cast<bf16x8*>(&xb[(size_t)token * 512 + dstg * 8]) = o;
  } else {
    int gid = (blockIdx.x - 4096) * 256 + threadIdx.x;
    if (gid < 384 * 512) {
      int nrow = gid >> 9;
      int kdst = gid & 511;
      int ksrc = (kdst & ~56) | (((((kdst >> 3) & 7)) ^ (nrow & 7)) << 3);
      const float* src = (nrow < 128) ? wq : ((nrow < 256) ? wk : wv);
      int n = nrow & 127;
      wqkvt[gid] = (bf16_t)src[ksrc * 128 + n];
    } else {
      int g = gid - 384 * 512;
      int nrow = g >> 7;   // d index (row)
      int kdst = g & 127;  // u index (col)
      int ksrc = (kdst & ~56) | (((((kdst >> 3) & 7)) ^ (nrow & 7)) << 3);
      wot[g] = (bf16_t)wo[ksrc * 512 + nrow];
    }
  }
}

// ---------------------------------------------------------------------------
// Kernel 2: QKV GEMM (128x64 tiles, async swizzled staging).
// ---------------------------------------------------------------------------
__global__ __launch_bounds__(256, 4) void qkv_gemm_kernel(const bf16_t* __restrict__ xb,
                                                          const bf16_t* __restrict__ wqkvt,
                                                          bf16_t* __restrict__ Q,
                                                          bf16_t* __restrict__ K,
                                                          bf16_t* __restrict__ Vt) {
  __shared__ bf16_t lA[128 * 64];
  __shared__ bf16_t lB[64 * 64];
  const int lid = (blockIdx.x & 7) * 96 + (blockIdx.x >> 3);  // bijective, 768=8*96
  const int m0 = (lid / 6) * 128;
  const int n0 = (lid % 6) * 64;
  const int tid = threadIdx.x;
  const int w = tid >> 6, lane = tid & 63;
  const int quad = lane >> 4, l15 = lane & 15;

  floatx4 zero4 = {0.f, 0.f, 0.f, 0.f};
  floatx4 acc[2][4];
#pragma unroll
  for (int mi = 0; mi < 2; mi++)
#pragma unroll
    for (int nt = 0; nt < 4; nt++) acc[mi][nt] = zero4;

  for (int kc = 0; kc < 512; kc += 64) {
    __syncthreads();
#pragma unroll
    for (int i = 0; i < 4; i++) {
      int t = tid + i * 256;       // A granule 0..1023
      int r = t >> 3, g = t & 7;
      gld_lds16(&xb[(size_t)(m0 + r) * 512 + kc + g * 8], &lA[t * 8]);
    }
#pragma unroll
    for (int i = 0; i < 2; i++) {
      int t = tid + i * 256;       // B granule 0..511
      int r = t >> 3, g = t & 7;
      gld_lds16(&wqkvt[(size_t)(n0 + r) * 512 + kc + g * 8], &lB[t * 8]);
    }
    asm volatile("s_waitcnt vmcnt(0)" ::: "memory");
    __syncthreads();
#pragma unroll
    for (int kb = 0; kb < 2; kb++) {
      bf16x8 bfr[4];
#pragma unroll
      for (int nt = 0; nt < 4; nt++)
        bfr[nt] = *reinterpret_cast<const bf16x8*>(
            &lB[(nt * 16 + l15) * 64 + SW(l15, kb * 4 + quad)]);
#pragma unroll
      for (int mi = 0; mi < 2; mi++) {
        bf16x8 a = *reinterpret_cast<const bf16x8*>(
            &lA[(w * 32 + mi * 16 + l15) * 64 + SW(l15, kb * 4 + quad)]);
#pragma unroll
        for (int nt = 0; nt < 4; nt++)
          acc[mi][nt] = mfma16(a, bfr[nt], acc[mi][nt]);
      }
    }
  }

#pragma unroll
  for (int mi = 0; mi < 2; mi++)
#pragma unroll
    for (int nt = 0; nt < 4; nt++) {
      int n = n0 + nt * 16 + l15;
#pragma unroll
      for (int r = 0; r < 4; r++) {
        int token = m0 + w * 32 + mi * 16 + quad * 4 + r;
        bf16_t h = (bf16_t)acc[mi][nt][r];
        if (n < 128) {
          Q[(size_t)token * 128 + n] = h;
        } else if (n < 256) {
          int nk = n - 128;
          int nsw = (nk & ~56) | ((((nk >> 3) & 7) ^ (token & 7)) << 3);
          K[(size_t)token * 128 + nsw] = h;
        } else {
          int bidx = token >> 11;
          int t = token & 2047;
          int u = n - 256;
          int tsw = (t & ~56) | ((((t >> 3) & 7) ^ (u & 7)) << 3);
          Vt[((size_t)bidx * 128 + u) * 2048 + tsw] = h;
        }
      }
    }
}

// ---------------------------------------------------------------------------
// Kernel 3: split-K flash attention, 32x32x16 MFMA core, in-register P.
// (verified round 7; unchanged)
// ---------------------------------------------------------------------------
__global__ __launch_bounds__(256, 2) void attn_kernel(const bf16_t* __restrict__ Q,
                                                      const bf16_t* __restrict__ K,
                                                      const bf16_t* __restrict__ Vt,
                                                      bf16_t* __restrict__ Op,
                                                      float* __restrict__ ml) {
  __shared__ bf16_t lK[2][64 * 128];
  __shared__ bf16_t lV[2][128 * 64];

  const int lid = (blockIdx.x & 7) * 64 + (blockIdx.x >> 3);
  const int qb = lid & 15;
  const int bs = lid >> 4;      // 0..31
  const int b = bs >> 2;
  const int s = bs & 3;
  const int tid = threadIdx.x;
  const int w = tid >> 6, lane = tid & 63;
  const int l31 = lane & 31, h = lane >> 5;
  const float c = 0.08838834764831845f * 1.4426950408889634f;  // 1/sqrt(U)*log2e

  bf16x8 qf[8];
  {
    const bf16_t* qrow =
        &Q[((size_t)b * NN + qb * 128 + w * 32 + l31) * 128 + h * 8];
#pragma unroll
    for (int kb = 0; kb < 8; kb++)
      qf[kb] = *reinterpret_cast<const bf16x8*>(qrow + kb * 16);
  }

  float l_part = 0.f;
  floatx16 accO[4];
#pragma unroll
  for (int ut = 0; ut < 4; ut++)
#pragma unroll
    for (int i = 0; i < 16; i++) accO[ut][i] = 0.f;

  const int kt0 = s * KSPLIT;
  const bf16_t* kbase = &K[(size_t)b * NN * 128];
  const bf16_t* vbase = &Vt[(size_t)b * 128 * 2048];

  {
    const bf16_t* ksrc = kbase + (size_t)kt0 * 128;
#pragma unroll
    for (int i = 0; i < 4; i++) {
      int t = tid + i * 256;
      gld_lds16(ksrc + (size_t)t * 8, &lK[0][t * 8]);
    }
#pragma unroll
    for (int i = 0; i < 4; i++) {
      int t = tid + i * 256;
      int r = t >> 3, g = t & 7;
      gld_lds16(vbase + (size_t)r * 2048 + kt0 + g * 8, &lV[0][t * 8]);
    }
  }
  asm volatile("s_waitcnt vmcnt(0)" ::: "memory");
  __syncthreads();

  int cur = 0;
  for (int kt = kt0; kt < kt0 + KSPLIT; kt += 64) {
    if (kt + 64 < kt0 + KSPLIT) {
      const int nxt = kt + 64;
      const bf16_t* ksrc = kbase + (size_t)nxt * 128;
#pragma unroll
      for (int i = 0; i < 4; i++) {
        int t = tid + i * 256;
        gld_lds16(ksrc + (size_t)t * 8, &lK[cur ^ 1][t * 8]);
      }
#pragma unroll
      for (int i = 0; i < 4; i++) {
        int t = tid + i * 256;
        int r = t >> 3, g = t & 7;
        gld_lds16(vbase + (size_t)r * 2048 + nxt + g * 8, &lV[cur ^ 1][t * 8]);
      }
    }

    floatx16 accS[2];
#pragma unroll
    for (int km = 0; km < 2; km++)
#pragma unroll
      for (int i = 0; i < 16; i++) accS[km][i] = 0.f;

    __builtin_amdgcn_s_setprio(1);
#pragma unroll
    for (int kb = 0; kb < 8; kb++) {
#pragma unroll
      for (int km = 0; km < 2; km++) {
        int r = km * 32 + l31;
        bf16x8 kf = *reinterpret_cast<const bf16x8*>(
            &lK[cur][r * 128 + SW(r, kb * 2 + h)]);
        accS[km] = mfma32(kf, qf[kb], accS[km]);
      }
    }
    __builtin_amdgcn_s_setprio(0);

    bf16x8 pa[4];
#pragma unroll
    for (int km = 0; km < 2; km++) {
      float p[16];
#pragma unroll
      for (int i = 0; i < 16; i++) {
        p[i] = __builtin_amdgcn_exp2f(accS[km][i] * c);
        l_part += p[i];
      }
#pragma unroll
      for (int s2 = 0; s2 < 2; s2++) {
        unsigned int w00 = pk2(p[8 * s2 + 0], p[8 * s2 + 1]);
        unsigned int w01 = pk2(p[8 * s2 + 2], p[8 * s2 + 3]);
        unsigned int w10 = pk2(p[8 * s2 + 4], p[8 * s2 + 5]);
        unsigned int w11 = pk2(p[8 * s2 + 6], p[8 * s2 + 7]);
        unsigned int s0 = h ? w00 : w10;
        unsigned int s1 = h ? w01 : w11;
        unsigned int r0 = __shfl_xor(s0, 32);
        unsigned int r1 = __shfl_xor(s1, 32);
        union { unsigned int u[4]; bf16x8 v; } af;
        af.u[0] = h ? r0 : w00;
        af.u[1] = h ? r1 : w01;
        af.u[2] = h ? w10 : r0;
        af.u[3] = h ? w11 : r1;
        pa[km * 2 + s2] = af.v;
      }
    }

    __builtin_amdgcn_s_setprio(1);
#pragma unroll
    for (int ut = 0; ut < 4; ut++) {
#pragma unroll
      for (int ks = 0; ks < 4; ks++) {
        int ur = ut * 32 + l31;
        bf16x8 vf = *reinterpret_cast<const bf16x8*>(
            &lV[cur][ur * 64 + SW(ur, ks * 2 + h)]);
        accO[ut] = mfma32(pa[ks], vf, accO[ut]);
      }
    }
    __builtin_amdgcn_s_setprio(0);

    asm volatile("s_waitcnt vmcnt(0)" ::: "memory");
    __syncthreads();
    cur ^= 1;
  }

  l_part += __shfl_xor(l_part, 32);

  size_t base = ((size_t)(b * 16 + qb) * SPLITS + s);
  bf16_t* op = Op + base * (128 * 128);
#pragma unroll
  for (int ut = 0; ut < 4; ut++)
#pragma unroll
    for (int i = 0; i < 16; i++) {
      int qr = w * 32 + (i & 3) + 8 * (i >> 2) + 4 * h;
      op[qr * 128 + ut * 32 + l31] = (bf16_t)accO[ut][i];
    }
  if (h == 0) ml[base * 128 + w * 32 + l31] = l_part;
}

// ---------------------------------------------------------------------------
// Kernel 4: fused merge + out GEMM + bias + residual.
// Block: 512 thr / 8 waves, 64 tokens x full 512 outputs. Grid 256 (1/CU).
// Stages ALL of Wot (128KB) via gld_lds; merges the 4 split-partials of its
// 64 tokens from Op into lA (16KB, swizzled) in registers; single barrier;
// then 16x16x32 MFMA. ctx roundtrip and merge kernel eliminated.
// LDS 144KB -> 1 block/CU.
// ---------------------------------------------------------------------------
__global__ __launch_bounds__(512, 1) void out_merge_gemm_kernel(
    const bf16_t* __restrict__ Op, const float* __restrict__ ml,
    const bf16_t* __restrict__ wot, const float* __restrict__ bo,
    const float* __restrict__ x0, float* __restrict__ out) {
  __shared__ bf16_t lW[512 * 128];   // 128KB: all of W_o (rows d, k=u)
  __shared__ bf16_t lA[64 * 128];    // 16KB: merged ctx tile (rows token, k=u)

  const int tid = threadIdx.x;
  const int w = tid >> 6, lane = tid & 63;
  const int quad = lane >> 4, l15 = lane & 15;
  const int m0 = blockIdx.x * 64;
  const int b = blockIdx.x >> 5;            // 32 blocks per batch
  const int qb = (blockIdx.x >> 1) & 15;
  const int half = blockIdx.x & 1;          // which 64-row half of the qb block
  const size_t ebase = ((size_t)(b * 16 + qb)) * SPLITS;

  // stage all of W_o (pre-swizzled global -> linear LDS copy)
#pragma unroll
  for (int i = 0; i < 16; i++) {
    int tg = tid + i * 512;                 // granule 0..8191
    gld_lds16(&wot[(size_t)tg * 8], &lW[tg * 8]);
  }

  // merge this block's 64 tokens: 1024 granule-positions over 512 threads
#pragma unroll
  for (int j = 0; j < 2; j++) {
    int ql = j * 32 + (tid >> 4);           // local token 0..63
    int g = tid & 15;                       // u-granule 0..15
    int qrow = half * 64 + ql;              // row within the qb 128-block
    float L = 0.f;
    float o[8];
#pragma unroll
    for (int k = 0; k < 8; k++) o[k] = 0.f;
#pragma unroll
    for (int s = 0; s < SPLITS; s++) {
      size_t e = ebase + s;
      L += ml[e * 128 + qrow];
      bf16x8 ch = *reinterpret_cast<const bf16x8*>(
          &Op[(e * 128 + qrow) * 128 + g * 8]);
#pragma unroll
      for (int k = 0; k < 8; k++) o[k] += (float)ch[k];
    }
    float inv = 1.0f / L;
    int gsw = (g & 8) | ((g & 7) ^ (ql & 7));
    bf16x8 ch;
#pragma unroll
    for (int k = 0; k < 8; k++) ch[k] = (bf16_t)(o[k] * inv);
    *reinterpret_cast<bf16x8*>(&lA[ql * 128 + gsw * 8]) = ch;
  }

  asm volatile("s_waitcnt vmcnt(0)" ::: "memory");
  __syncthreads();

  // GEMM: wave w owns n-range [w*64, w*64+64); all 64 rows (4 row-frags).
  floatx4 zero4 = {0.f, 0.f, 0.f, 0.f};
  floatx4 acc[4][4];
#pragma unroll
  for (int mi = 0; mi < 4; mi++)
#pragma unroll
    for (int nt = 0; nt < 4; nt++) acc[mi][nt] = zero4;

#pragma unroll
  for (int kb = 0; kb < 4; kb++) {
    bf16x8 bfr[4];
#pragma unroll
    for (int nt = 0; nt < 4; nt++)
      bfr[nt] = *reinterpret_cast<const bf16x8*>(
          &lW[(w * 64 + nt * 16 + l15) * 128 + SW(l15, kb * 4 + quad)]);
#pragma unroll
    for (int mi = 0; mi < 4; mi++) {
      bf16x8 a = *reinterpret_cast<const bf16x8*>(
          &lA[(mi * 16 + l15) * 128 + SW(l15, kb * 4 + quad)]);
#pragma unroll
      for (int nt = 0; nt < 4; nt++)
        acc[mi][nt] = mfma16(a, bfr[nt], acc[mi][nt]);
    }
  }

#pragma unroll
  for (int mi = 0; mi < 4; mi++)
#pragma unroll
    for (int nt = 0; nt < 4; nt++) {
      int n = w * 64 + nt * 16 + l15;
      float bias = bo[n];
#pragma unroll
      for (int r = 0; r < 4; r++) {
        size_t m = m0 + mi * 16 + quad * 4 + r;
        out[m * 512 + n] = acc[mi][nt][r] + bias + x0[m * 512 + n];
      }
    }
}

// ---------------------------------------------------------------------------
extern "C" void kernel_launch(void* const* d_in, const int* in_sizes, int n_in,
                              void* d_out, int out_size, void* d_ws, size_t ws_size,
                              hipStream_t stream) {
  const float* x  = (const float*)d_in[0];
  const float* wq = (const float*)d_in[1];
  const float* wk = (const float*)d_in[2];
  const float* wv = (const float*)d_in[3];
  const float* wo = (const float*)d_in[4];
  const float* bo = (const float*)d_in[5];
  float* out = (float*)d_out;

  char* ws = (char*)d_ws;
  // layout (bytes):
  //   0        Qb    4MB   [16384,128] bf16 (unswizzled)
  //   4M       Kb    4MB   (granule-swizzled)
  //   8M       Vt    4MB   [8][128][2048] bf16 (granule-swizzled)
  //   12M      (free, was Ctx)
  //   16M      Wqkvt 384KB (granule-swizzled)
  //   16M+384K Wot   128KB (granule-swizzled)
  //   16.5M    Xb    16MB  (granule-swizzled; dead after qkv_gemm)
  //   16.5M    Op    16MB  [128 blk][4 split][128][128] bf16 (aliases Xb)
  //   48.5M    ml    256KB [128 blk][4 split][128] fp32
  bf16_t* Qb    = (bf16_t*)(ws);
  bf16_t* Kb    = (bf16_t*)(ws + 4194304);
  bf16_t* Vt    = (bf16_t*)(ws + 2 * 4194304);
  bf16_t* Wqkvt = (bf16_t*)(ws + 4 * 4194304);
  bf16_t* Wot   = (bf16_t*)(ws + 4 * 4194304 + 393216);
  bf16_t* Xb    = (bf16_t*)(ws + 4 * 4194304 + 524288);
  bf16_t* Op    = (bf16_t*)(ws + 4 * 4194304 + 524288);   // aliases Xb
  float*  ml    = (float*)(ws + 4 * 4194304 + 524288 + 33554432);

  prep_kernel<<<5120, 256, 0, stream>>>(x, wq, wk, wv, wo, Xb, Wqkvt, Wot);
  qkv_gemm_kernel<<<768, 256, 0, stream>>>(Xb, Wqkvt, Qb, Kb, Vt);
  attn_kernel<<<512, 256, 0, stream>>>(Qb, Kb, Vt, Op, ml);
  out_merge_gemm_kernel<<<256, 512, 0, stream>>>(Op, ml, Wot, bo, x, out);
}